// Round 3
// baseline (474.726 us; speedup 1.0000x reference)
//
#include <hip/hip_runtime.h>
#include <math.h>

// Problem constants
constexpr int Bq = 128;   // batch
constexpr int Nn = 512;   // nodes
constexpr int Dd = 300;   // feature dim
constexpr int Aa = 32;    // attention dim
constexpr int DT = 304;   // d padded to 19 tiles of 16 for MFMA N-dim

typedef __attribute__((ext_vector_type(8))) short short8;   // 8 bf16 (4 VGPRs)
typedef __attribute__((ext_vector_type(4))) float float4v;  // MFMA acc
typedef __attribute__((ext_vector_type(4))) unsigned int uint4v;

static __device__ __forceinline__ ushort f2bf(float x) {
    unsigned u = __float_as_uint(x);
    return (ushort)((u + 0x7FFF + ((u >> 16) & 1)) >> 16);   // RNE
}

// ---------------- Kernel 1: Q/K projection (bf16 out) + bf16 X^T emission ----------------
constexpr int KB_ROWS = 128;
constexpr int DCHUNK = 100;      // 300 = 3 x 100
constexpr int XS_STRIDE = 102;

__global__ __launch_bounds__(256) void proj_qk(
    const float* __restrict__ X, const float* __restrict__ Wq,
    const float* __restrict__ Wk, ushort* __restrict__ Qo, ushort* __restrict__ Ko,
    ushort* __restrict__ XbfT)
{
    __shared__ float xs[KB_ROWS * XS_STRIDE];  // ~51 KB
    const int b  = blockIdx.y;
    const int n0 = blockIdx.x * KB_ROWS;
    const int t  = threadIdx.x;
    const int c  = t & 15;
    const int r  = t >> 4;
    const int a4 = c * 4;
    const int rbase = r * 8;
    const float* Wbase = (a4 < Aa) ? (Wq + a4) : (Wk + (a4 - Aa));
    const float* Xb = X + ((size_t)(b * Nn + n0)) * Dd;

    float4 acc[8];
#pragma unroll
    for (int j = 0; j < 8; ++j) acc[j] = make_float4(0.f, 0.f, 0.f, 0.f);

    for (int d0 = 0; d0 < Dd; d0 += DCHUNK) {
        for (int l = t; l < KB_ROWS * (DCHUNK / 2); l += 256) {
            int row = l / (DCHUNK / 2);
            int dd2 = l - row * (DCHUNK / 2);
            *(float2*)(xs + row * XS_STRIDE + dd2 * 2) =
                *(const float2*)(Xb + (size_t)row * Dd + d0 + dd2 * 2);
        }
        __syncthreads();
        for (int dd = 0; dd < DCHUNK; ++dd) {
            float4 w4 = *(const float4*)(Wbase + (size_t)(d0 + dd) * Aa);
#pragma unroll
            for (int j = 0; j < 8; ++j) {
                float xv = xs[(rbase + j) * XS_STRIDE + dd];
                acc[j].x += xv * w4.x; acc[j].y += xv * w4.y;
                acc[j].z += xv * w4.z; acc[j].w += xv * w4.w;
            }
        }
        // emit bf16 transposed chunk: XbfT[b][d0+dd][n0+row]
        for (int l = t; l < KB_ROWS * DCHUNK; l += 256) {
            int dd  = l >> 7;        // 12800 = 100 x 128
            int row = l & 127;
            XbfT[((size_t)b * DT + d0 + dd) * Nn + n0 + row] =
                f2bf(xs[row * XS_STRIDE + dd]);
        }
        __syncthreads();
    }

    ushort* Obase = (a4 < Aa) ? (Qo + a4) : (Ko + (a4 - Aa));
#pragma unroll
    for (int j = 0; j < 8; ++j) {
        int n = n0 + rbase + j;
        ushort4 o;
        o.x = f2bf(acc[j].x); o.y = f2bf(acc[j].y);
        o.z = f2bf(acc[j].z); o.w = f2bf(acc[j].w);
        *(ushort4*)(Obase + (size_t)(b * Nn + n) * Aa) = o;
    }
}

// ---------------- Kernel 2: barrier-free, LDS-free attention ----------------
// v3: swapped QK^T (mfma(K,Q) -> S^T) makes each q-row lane-local by column.
//     Each wave owns 16 q-rows x all 512 cols: P packed bf16 in 64 VGPRs,
//     C-layout -> A-frag transpose via 8 ds_bpermute + 4 cndmask per ks.
//     Adjacency read directly in fragment layout (coalesced float4, prefetched).
//     Zero LDS, zero barriers; waves fully independent; deep ILP preserved.

__global__ __launch_bounds__(256, 3) void attn_kernel(
    const float* __restrict__ Adj, const ushort* __restrict__ Qbf,
    const ushort* __restrict__ Kbf, const ushort* __restrict__ XbfT,
    float* __restrict__ Out)
{
    // XCD swizzle: all 8 row-tiles of a batch stream on one XCD (L2 reuse of
    // that batch's XbfT slice (311 KB) + Kbf/Qbf slices).
    const int blk  = blockIdx.x;
    const int xcd  = blk & 7;
    const int idx  = blk >> 3;                 // 0..127
    const int b    = ((idx >> 3) << 3) | xcd;  // batch
    const int n0   = (idx & 7) * 64;           // 64-row block tile

    const int t    = threadIdx.x;
    const int lane = t & 63;
    const int wv   = t >> 6;
    const int dl   = lane & 15;
    const int quad = (lane >> 4) & 3;
    const int n0w  = n0 + wv * 16;             // this wave's 16 q-rows

    // Q as B-operand fragment: lane holds Q[q=dl][a=quad*8..+7]
    short8 qfr = *(const short8*)(Qbf + ((size_t)(b * Nn + n0w + dl)) * Aa + quad * 8);

    // K rows as A-operand: row m0+dl (and +16), k = quad*8..+7
    const ushort* Kb   = Kbf + (size_t)b * Nn * Aa + (size_t)dl * Aa + quad * 8;
    // adjacency in C-frag layout: lane needs adj[q=dl][m0 + 16h + quad*4 + r]
    const float*  arow = Adj + ((size_t)b * Nn + n0w + dl) * Nn + quad * 4;

    uint4v pf[16];            // packed bf16 P, 2 values/word: [ks]{h0r01,h0r23,h1r01,h1r23}
    float dsum = 0.f;

    short8 kf0 = *(const short8*)(Kb);
    short8 kf1 = *(const short8*)(Kb + (size_t)16 * Aa);
    float4 ad0 = *(const float4*)(arow);
    float4 ad1 = *(const float4*)(arow + 16);

    // ---- Phase 1: S^T = mfma(K, Q); e = adj ? exp(S) : 1, packed to bf16 regs ----
#pragma unroll
    for (int ks = 0; ks < 16; ++ks) {
        short8 ck0 = kf0, ck1 = kf1;
        float4 c0 = ad0, c1 = ad1;
        if (ks < 15) {
            const int m0n = (ks + 1) * 32;
            kf0 = *(const short8*)(Kb + (size_t)m0n * Aa);
            kf1 = *(const short8*)(Kb + (size_t)(m0n + 16) * Aa);
            ad0 = *(const float4*)(arow + m0n);
            ad1 = *(const float4*)(arow + m0n + 16);
        }
        float4v z = {0.f, 0.f, 0.f, 0.f};
        // D[i=m][j=q]: col=lane&15=q, row=quad*4+r = m within 16-row half
        float4v s0 = __builtin_amdgcn_mfma_f32_16x16x32_bf16(ck0, qfr, z, 0, 0, 0);
        float4v s1 = __builtin_amdgcn_mfma_f32_16x16x32_bf16(ck1, qfr, z, 0, 0, 0);
        float e0 = (c0.x != 0.f) ? __expf(s0[0]) : 1.0f;   // adj==0 -> e=1 exactly
        float e1 = (c0.y != 0.f) ? __expf(s0[1]) : 1.0f;
        float e2 = (c0.z != 0.f) ? __expf(s0[2]) : 1.0f;
        float e3 = (c0.w != 0.f) ? __expf(s0[3]) : 1.0f;
        float e4 = (c1.x != 0.f) ? __expf(s1[0]) : 1.0f;
        float e5 = (c1.y != 0.f) ? __expf(s1[1]) : 1.0f;
        float e6 = (c1.z != 0.f) ? __expf(s1[2]) : 1.0f;
        float e7 = (c1.w != 0.f) ? __expf(s1[3]) : 1.0f;
        dsum += ((e0 + e1) + (e2 + e3)) + ((e4 + e5) + (e6 + e7));
        pf[ks][0] = (unsigned)f2bf(e0) | ((unsigned)f2bf(e1) << 16);
        pf[ks][1] = (unsigned)f2bf(e2) | ((unsigned)f2bf(e3) << 16);
        pf[ks][2] = (unsigned)f2bf(e4) | ((unsigned)f2bf(e5) << 16);
        pf[ks][3] = (unsigned)f2bf(e6) | ((unsigned)f2bf(e7) << 16);
    }

    // ---- Softmax denominators: lane-local + 2 shuffles (rows are lane-local!) ----
    dsum += __shfl_xor(dsum, 16);
    dsum += __shfl_xor(dsum, 32);
    const float inv = 1.0f / dsum;            // denom for q = dl, in all 4 quad-lanes
    float invr[4];
#pragma unroll
    for (int r = 0; r < 4; ++r) invr[r] = __shfl(inv, quad * 4 + r);  // for output row q=quad*4+r

    // ---- In-register transpose: C-layout P -> A-fragment layout ----
    // Target lane (dl,quad), elem j: m = 32ks + quad*8 + j
    //   = src lane (dl + 16*quad_src), half h'=quad>>1, reg r'=j&3,
    //     quad_src = 2*(quad&1) + (j>>2)
    const int a0   = (dl + ((lane >> 4) & 1) * 32) << 2;   // src lane * 4 (j=0..3)
    const int a1   = a0 + 64;                              // +16 lanes    (j=4..7)
    const bool hsel = (lane >> 5) & 1;                     // h' = quad>>1
#pragma unroll
    for (int ks = 0; ks < 16; ++ks) {
        int p0 = (int)pf[ks][0], p1 = (int)pf[ks][1];
        int p2 = (int)pf[ks][2], p3 = (int)pf[ks][3];
        int t00 = __builtin_amdgcn_ds_bpermute(a0, p0);
        int t01 = __builtin_amdgcn_ds_bpermute(a0, p1);
        int t10 = __builtin_amdgcn_ds_bpermute(a0, p2);
        int t11 = __builtin_amdgcn_ds_bpermute(a0, p3);
        int t20 = __builtin_amdgcn_ds_bpermute(a1, p0);
        int t21 = __builtin_amdgcn_ds_bpermute(a1, p1);
        int t30 = __builtin_amdgcn_ds_bpermute(a1, p2);
        int t31 = __builtin_amdgcn_ds_bpermute(a1, p3);
        pf[ks][0] = (unsigned)(hsel ? t10 : t00);
        pf[ks][1] = (unsigned)(hsel ? t11 : t01);
        pf[ks][2] = (unsigned)(hsel ? t30 : t20);
        pf[ks][3] = (unsigned)(hsel ? t31 : t21);
    }

    // ---- Phase 3: Out[q][d] = inv[q] * sum_m P[q][m] * X[m][d], P from VGPRs ----
    const ushort* Xw = XbfT + (size_t)b * DT * Nn + (size_t)dl * Nn + quad * 8;

#pragma unroll 1
    for (int p = 0; p < 9; ++p) {
        const ushort* ba = Xw + (size_t)(2 * p) * 16 * Nn;
        const ushort* bb = ba + (size_t)16 * Nn;
        short8 xa = *(const short8*)(ba);
        short8 xb = *(const short8*)(bb);
        float4v acca = {0.f, 0.f, 0.f, 0.f};
        float4v accb = {0.f, 0.f, 0.f, 0.f};
#pragma unroll
        for (int ks = 0; ks < 16; ++ks) {
            short8 cxa = xa, cxb = xb;
            if (ks < 15) {
                xa = *(const short8*)(ba + (ks + 1) * 32);
                xb = *(const short8*)(bb + (ks + 1) * 32);
            }
            short8 af = __builtin_bit_cast(short8, pf[ks]);
            acca = __builtin_amdgcn_mfma_f32_16x16x32_bf16(af, cxa, acca, 0, 0, 0);
            accb = __builtin_amdgcn_mfma_f32_16x16x32_bf16(af, cxb, accb, 0, 0, 0);
        }
        const int da = 2 * p * 16 + dl;     // <= 271 < 300, no guard needed
        const int db = da + 16;             // <= 287 < 300
#pragma unroll
        for (int r = 0; r < 4; ++r) {
            float* orow = Out + ((size_t)(b * Nn + n0w + quad * 4 + r)) * Dd;
            orow[da] = acca[r] * invr[r];
            orow[db] = accb[r] * invr[r];
        }
    }
    // tail tile dt=18 (d = 288..303, store only d<300)
    {
        const ushort* ba = Xw + (size_t)288 * Nn;
        short8 xa = *(const short8*)(ba);
        float4v acca = {0.f, 0.f, 0.f, 0.f};
#pragma unroll
        for (int ks = 0; ks < 16; ++ks) {
            short8 cxa = xa;
            if (ks < 15) xa = *(const short8*)(ba + (ks + 1) * 32);
            short8 af = __builtin_bit_cast(short8, pf[ks]);
            acca = __builtin_amdgcn_mfma_f32_16x16x32_bf16(af, cxa, acca, 0, 0, 0);
        }
        const int da = 288 + dl;
        if (da < Dd) {
#pragma unroll
            for (int r = 0; r < 4; ++r) {
                float* orow = Out + ((size_t)(b * Nn + n0w + quad * 4 + r)) * Dd;
                orow[da] = acca[r] * invr[r];
            }
        }
    }
}

// ---------------- launch ----------------
extern "C" void kernel_launch(void* const* d_in, const int* in_sizes, int n_in,
                              void* d_out, int out_size, void* d_ws, size_t ws_size,
                              hipStream_t stream) {
    const float* X   = (const float*)d_in[0];   // [128,512,300]
    const float* Adj = (const float*)d_in[1];   // [128,512,512]
    const float* Wq  = (const float*)d_in[2];   // [300,32]
    const float* Wk  = (const float*)d_in[3];   // [300,32]
    float* Out = (float*)d_out;                 // [128,512,300]

    ushort* Qbf  = (ushort*)d_ws;                                      // 4 MB
    ushort* Kbf  = (ushort*)((char*)d_ws + (size_t)4 * 1024 * 1024);   // 4 MB
    ushort* XbfT = (ushort*)((char*)d_ws + (size_t)8 * 1024 * 1024);   // ~39.9 MB

    proj_qk<<<dim3(Nn / KB_ROWS, Bq), 256, 0, stream>>>(X, Wq, Wk, Qbf, Kbf, XbfT);
    attn_kernel<<<dim3(Bq * Nn / 64), 256, 0, stream>>>(Adj, Qbf, Kbf, XbfT, Out);
}

// Round 4
// 407.175 us; speedup vs baseline: 1.1659x; 1.1659x over previous
//
#include <hip/hip_runtime.h>
#include <math.h>

// Problem constants
constexpr int Bq = 128;   // batch
constexpr int Nn = 512;   // nodes
constexpr int Dd = 300;   // feature dim
constexpr int Aa = 32;    // attention dim
constexpr int DT = 304;   // d padded to 19 tiles of 16 for MFMA N-dim

typedef __attribute__((ext_vector_type(8))) short short8;   // 8 bf16 (4 VGPRs)
typedef __attribute__((ext_vector_type(4))) float float4v;  // MFMA acc

static __device__ __forceinline__ ushort f2bf(float x) {
    unsigned u = __float_as_uint(x);
    return (ushort)((u + 0x7FFF + ((u >> 16) & 1)) >> 16);   // RNE
}

// ---------------- Kernel 1: Q/K projection (bf16 out) + bf16 X^T emission ----------------
constexpr int KB_ROWS = 128;
constexpr int DCHUNK = 100;      // 300 = 3 x 100
constexpr int XS_STRIDE = 102;

__global__ __launch_bounds__(256) void proj_qk(
    const float* __restrict__ X, const float* __restrict__ Wq,
    const float* __restrict__ Wk, ushort* __restrict__ Qo, ushort* __restrict__ Ko,
    ushort* __restrict__ XbfT)
{
    __shared__ float xs[KB_ROWS * XS_STRIDE];  // ~51 KB
    const int b  = blockIdx.y;
    const int n0 = blockIdx.x * KB_ROWS;
    const int t  = threadIdx.x;
    const int c  = t & 15;
    const int r  = t >> 4;
    const int a4 = c * 4;
    const int rbase = r * 8;
    const float* Wbase = (a4 < Aa) ? (Wq + a4) : (Wk + (a4 - Aa));
    const float* Xb = X + ((size_t)(b * Nn + n0)) * Dd;

    float4 acc[8];
#pragma unroll
    for (int j = 0; j < 8; ++j) acc[j] = make_float4(0.f, 0.f, 0.f, 0.f);

    for (int d0 = 0; d0 < Dd; d0 += DCHUNK) {
        for (int l = t; l < KB_ROWS * (DCHUNK / 2); l += 256) {
            int row = l / (DCHUNK / 2);
            int dd2 = l - row * (DCHUNK / 2);
            *(float2*)(xs + row * XS_STRIDE + dd2 * 2) =
                *(const float2*)(Xb + (size_t)row * Dd + d0 + dd2 * 2);
        }
        __syncthreads();
        for (int dd = 0; dd < DCHUNK; ++dd) {
            float4 w4 = *(const float4*)(Wbase + (size_t)(d0 + dd) * Aa);
#pragma unroll
            for (int j = 0; j < 8; ++j) {
                float xv = xs[(rbase + j) * XS_STRIDE + dd];
                acc[j].x += xv * w4.x; acc[j].y += xv * w4.y;
                acc[j].z += xv * w4.z; acc[j].w += xv * w4.w;
            }
        }
        // emit bf16 transposed chunk: XbfT[b][d0+dd][n0+row]
        for (int l = t; l < KB_ROWS * DCHUNK; l += 256) {
            int dd  = l >> 7;        // 12800 = 100 x 128
            int row = l & 127;
            XbfT[((size_t)b * DT + d0 + dd) * Nn + n0 + row] =
                f2bf(xs[row * XS_STRIDE + dd]);
        }
        __syncthreads();
    }

    ushort* Obase = (a4 < Aa) ? (Qo + a4) : (Ko + (a4 - Aa));
#pragma unroll
    for (int j = 0; j < 8; ++j) {
        int n = n0 + rbase + j;
        ushort4 o;
        o.x = f2bf(acc[j].x); o.y = f2bf(acc[j].y);
        o.z = f2bf(acc[j].z); o.w = f2bf(acc[j].w);
        *(ushort4*)(Obase + (size_t)(b * Nn + n) * Aa) = o;
    }
}

// ---------------- Kernel 2: cooperative attention, swapped-QK^T phase 1 ----------------
// v4 = v1 structure (4 waves co-op on 32 rows, fragA LDS, 1 barrier) with:
//  - phase 1 computes S^T = mfma(K,Q) (validated in v3): adjacency reads become
//    coalesced float4 (4 loads/ks-iter vs 16 scalars), P-writes become ds_write_b64
//    (4/ks-iter vs 16 b16), denominators lane-local (2 shuffles).
//  - phase 3 pairs two d-tiles per pass (2 LDS P-reads feed 4 MFMAs).
//  - launch_bounds(256,2): NO register squeeze (v2/v3 lesson: VGPR=52 kills ILP).
constexpr int TN = 32;

__global__ __launch_bounds__(256, 2) void attn_kernel(
    const float* __restrict__ Adj, const ushort* __restrict__ Qbf,
    const ushort* __restrict__ Kbf, const ushort* __restrict__ XbfT,
    float* __restrict__ Out)
{
    __shared__ __align__(16) ushort fragA[2 * 8192];   // 32 KB, A-frag-layout P (bf16)
    __shared__ __align__(16) float wsum[4][TN];

    // XCD swizzle: each XCD (blk%8) streams all 16 tiles of one batch consecutively
    const int blk  = blockIdx.x;
    const int b    = ((blk >> 7) << 3) | (blk & 7);
    const int n0   = ((blk >> 3) & 15) * TN;

    const int t    = threadIdx.x;
    const int lane = t & 63;
    const int wv   = t >> 6;
    const int dl   = lane & 15;
    const int quad = lane >> 4;

    // ---- Phase 1: S^T = mfma(K, Q); e = adj ? exp(S) : 1 -> fragA via b64 writes ----
    // D-layout (m89): col = lane&15 = q (B free dim), row = quad*4+r = m-local.
    short8 qfr[2];   // B-operand: Q rows n0+rs*16+dl, a = quad*8..+7
#pragma unroll
    for (int rs = 0; rs < 2; ++rs)
        qfr[rs] = *(const short8*)(Qbf + ((size_t)(b * Nn + n0 + rs * 16 + dl)) * Aa + quad * 8);

    const ushort* Kb    = Kbf + (size_t)b * Nn * Aa + (size_t)dl * Aa + quad * 8;
    const float*  arow0 = Adj + ((size_t)b * Nn + n0 + dl) * Nn + quad * 4;

    float dsum[2] = {0.f, 0.f};
    // A-frag write base: elem = rs*8192 + ks*512 + (2h+(quad>>1))*128 + dl*8 + (quad&1)*4 + r
    ushort* wpb = fragA + (quad >> 1) * 128 + dl * 8 + (quad & 1) * 4;

#pragma unroll
    for (int i = 0; i < 4; ++i) {
        const int ks = wv + i * 4;      // this wave's 4 ks-tiles (static trip count)
        const int m0 = ks * 32;
        short8 kf0 = *(const short8*)(Kb + (size_t)m0 * Aa);          // K rows m0+dl   (h=0)
        short8 kf1 = *(const short8*)(Kb + (size_t)(m0 + 16) * Aa);   // K rows m0+16+dl (h=1)
        ushort* wp = wpb + ks * 512;
#pragma unroll
        for (int rs = 0; rs < 2; ++rs) {
            const float* ar = arow0 + (size_t)rs * 16 * Nn + m0;   // adj[q=rs*16+dl][m0+quad*4..]
            float4 a0 = *(const float4*)(ar);          // h=0: m = m0+quad*4+r
            float4 a1 = *(const float4*)(ar + 16);     // h=1: m = m0+16+quad*4+r
            float4v z = {0.f, 0.f, 0.f, 0.f};
            float4v s0 = __builtin_amdgcn_mfma_f32_16x16x32_bf16(kf0, qfr[rs], z, 0, 0, 0);
            float4v s1 = __builtin_amdgcn_mfma_f32_16x16x32_bf16(kf1, qfr[rs], z, 0, 0, 0);
            float e0 = (a0.x != 0.f) ? __expf(s0[0]) : 1.0f;   // adj==0 -> e=1 exactly
            float e1 = (a0.y != 0.f) ? __expf(s0[1]) : 1.0f;
            float e2 = (a0.z != 0.f) ? __expf(s0[2]) : 1.0f;
            float e3 = (a0.w != 0.f) ? __expf(s0[3]) : 1.0f;
            float e4 = (a1.x != 0.f) ? __expf(s1[0]) : 1.0f;
            float e5 = (a1.y != 0.f) ? __expf(s1[1]) : 1.0f;
            float e6 = (a1.z != 0.f) ? __expf(s1[2]) : 1.0f;
            float e7 = (a1.w != 0.f) ? __expf(s1[3]) : 1.0f;
            dsum[rs] += ((e0 + e1) + (e2 + e3)) + ((e4 + e5) + (e6 + e7));
            uint2 w0, w1;
            w0.x = (unsigned)f2bf(e0) | ((unsigned)f2bf(e1) << 16);
            w0.y = (unsigned)f2bf(e2) | ((unsigned)f2bf(e3) << 16);
            w1.x = (unsigned)f2bf(e4) | ((unsigned)f2bf(e5) << 16);
            w1.y = (unsigned)f2bf(e6) | ((unsigned)f2bf(e7) << 16);
            *(uint2*)(wp + rs * 8192)       = w0;   // h=0 chunk
            *(uint2*)(wp + rs * 8192 + 256) = w1;   // h=1 chunk (+2*128 elems)
        }
    }

    // ---- Phase 2: denominators. q-rows are lane-local (col=dl) -> 2 shuffles/wave ----
#pragma unroll
    for (int rs = 0; rs < 2; ++rs) {
        float v = dsum[rs];
        v += __shfl_xor(v, 16);
        v += __shfl_xor(v, 32);
        if (lane < 16) wsum[wv][rs * 16 + lane] = v;
    }
    __syncthreads();

    // Each lane finishes the cross-wave sum itself (float4 LDS reads, no 2nd barrier)
    float invr0[4], invr1[4];
    {
        float4 s0 = *(const float4*)&wsum[0][quad * 4];
        float4 s1 = *(const float4*)&wsum[0][16 + quad * 4];
#pragma unroll
        for (int w = 1; w < 4; ++w) {
            float4 t0 = *(const float4*)&wsum[w][quad * 4];
            float4 t1 = *(const float4*)&wsum[w][16 + quad * 4];
            s0.x += t0.x; s0.y += t0.y; s0.z += t0.z; s0.w += t0.w;
            s1.x += t1.x; s1.y += t1.y; s1.z += t1.z; s1.w += t1.w;
        }
        invr0[0] = 1.0f / s0.x; invr0[1] = 1.0f / s0.y;
        invr0[2] = 1.0f / s0.z; invr0[3] = 1.0f / s0.w;
        invr1[0] = 1.0f / s1.x; invr1[1] = 1.0f / s1.y;
        invr1[2] = 1.0f / s1.z; invr1[3] = 1.0f / s1.w;
    }

    // ---- Phase 3: Out[i][d] = inv[i] * sum_m e[i][m] * X[m][d] via MFMA (paired tiles) ----
    const ushort* Xb  = XbfT + ((size_t)b * DT) * Nn;
    const ushort* afp = fragA + (size_t)lane * 8;

    for (int p = 0; p < 3; ++p) {
        const int dta = wv + p * 8;
        if (dta >= DT / 16) break;
        const int dtb = dta + 4;
        if (dtb < DT / 16) {
            const ushort* bba = Xb + (size_t)(dta * 16 + dl) * Nn + quad * 8;
            const ushort* bbb = Xb + (size_t)(dtb * 16 + dl) * Nn + quad * 8;
            float4v a0a = {0.f, 0.f, 0.f, 0.f};
            float4v a1a = {0.f, 0.f, 0.f, 0.f};
            float4v a0b = {0.f, 0.f, 0.f, 0.f};
            float4v a1b = {0.f, 0.f, 0.f, 0.f};
#pragma unroll
            for (int ks = 0; ks < 16; ++ks) {
                short8 bfa = *(const short8*)(bba + ks * 32);
                short8 bfb = *(const short8*)(bbb + ks * 32);
                short8 p0  = *(const short8*)(afp + ks * 512);
                short8 p1  = *(const short8*)(afp + 8192 + ks * 512);
                a0a = __builtin_amdgcn_mfma_f32_16x16x32_bf16(p0, bfa, a0a, 0, 0, 0);
                a1a = __builtin_amdgcn_mfma_f32_16x16x32_bf16(p1, bfa, a1a, 0, 0, 0);
                a0b = __builtin_amdgcn_mfma_f32_16x16x32_bf16(p0, bfb, a0b, 0, 0, 0);
                a1b = __builtin_amdgcn_mfma_f32_16x16x32_bf16(p1, bfb, a1b, 0, 0, 0);
            }
            const int da = dta * 16 + dl;   // <= 191, no guard needed
            const int db = dtb * 16 + dl;   // <= 255, no guard needed
#pragma unroll
            for (int r = 0; r < 4; ++r) {
                float* o0 = Out + ((size_t)(b * Nn + n0 + quad * 4 + r)) * Dd;
                float* o1 = Out + ((size_t)(b * Nn + n0 + 16 + quad * 4 + r)) * Dd;
                o0[da] = a0a[r] * invr0[r];
                o1[da] = a1a[r] * invr1[r];
                o0[db] = a0b[r] * invr0[r];
                o1[db] = a1b[r] * invr1[r];
            }
        } else {
            const ushort* bb = Xb + (size_t)(dta * 16 + dl) * Nn + quad * 8;
            float4v acc0 = {0.f, 0.f, 0.f, 0.f};
            float4v acc1 = {0.f, 0.f, 0.f, 0.f};
#pragma unroll
            for (int ks = 0; ks < 16; ++ks) {
                short8 bf = *(const short8*)(bb + ks * 32);
                short8 p0 = *(const short8*)(afp + ks * 512);
                short8 p1 = *(const short8*)(afp + 8192 + ks * 512);
                acc0 = __builtin_amdgcn_mfma_f32_16x16x32_bf16(p0, bf, acc0, 0, 0, 0);
                acc1 = __builtin_amdgcn_mfma_f32_16x16x32_bf16(p1, bf, acc1, 0, 0, 0);
            }
            const int d = dta * 16 + dl;
            if (d < Dd) {
#pragma unroll
                for (int r = 0; r < 4; ++r) {
                    Out[((size_t)(b * Nn + n0 + quad * 4 + r)) * Dd + d]      = acc0[r] * invr0[r];
                    Out[((size_t)(b * Nn + n0 + 16 + quad * 4 + r)) * Dd + d] = acc1[r] * invr1[r];
                }
            }
        }
    }
}

// ---------------- launch ----------------
extern "C" void kernel_launch(void* const* d_in, const int* in_sizes, int n_in,
                              void* d_out, int out_size, void* d_ws, size_t ws_size,
                              hipStream_t stream) {
    const float* X   = (const float*)d_in[0];   // [128,512,300]
    const float* Adj = (const float*)d_in[1];   // [128,512,512]
    const float* Wq  = (const float*)d_in[2];   // [300,32]
    const float* Wk  = (const float*)d_in[3];   // [300,32]
    float* Out = (float*)d_out;                 // [128,512,300]

    ushort* Qbf  = (ushort*)d_ws;                                      // 4 MB
    ushort* Kbf  = (ushort*)((char*)d_ws + (size_t)4 * 1024 * 1024);   // 4 MB
    ushort* XbfT = (ushort*)((char*)d_ws + (size_t)8 * 1024 * 1024);   // ~39.9 MB

    proj_qk<<<dim3(Nn / KB_ROWS, Bq), 256, 0, stream>>>(X, Wq, Wk, Qbf, Kbf, XbfT);
    attn_kernel<<<dim3(Bq * Nn / TN), 256, 0, stream>>>(Adj, Qbf, Kbf, XbfT, Out);
}